// Round 5
// baseline (792.381 us; speedup 1.0000x reference)
//
#include <hip/hip_runtime.h>

typedef _Float16 f16;
typedef __attribute__((ext_vector_type(2))) _Float16 f16x2;
typedef __attribute__((ext_vector_type(4))) int intx4;
typedef __attribute__((ext_vector_type(2))) float fltx2;

__device__ inline float2 h2f(unsigned u){
    f16x2 h = __builtin_bit_cast(f16x2, u);
    return make_float2((float)h.x, (float)h.y);
}

// ---------------- CSR build (padded to multiples of 16 per node) ----------------

__global__ __launch_bounds__(256) void k_count(const int* __restrict__ dst, int* __restrict__ cnt, int E){
    int e = blockIdx.x*256 + threadIdx.x;
    if (e < E) atomicAdd(&cnt[dst[e]], 1);
}

__global__ __launch_bounds__(256) void k_scan1(const int* __restrict__ cnt, int* __restrict__ rs,
                                               int* __restrict__ part, int N){
    __shared__ int sm[256];
    int t = threadIdx.x;
    int i = blockIdx.x*256 + t;
    int c = (i < N) ? ((cnt[i] + 15) & ~15) : 0;
    sm[t] = c;
    __syncthreads();
    for (int off = 1; off < 256; off <<= 1){
        int v = (t >= off) ? sm[t-off] : 0;
        __syncthreads();
        sm[t] += v;
        __syncthreads();
    }
    if (i < N) rs[i] = sm[t] - c;
    if (t == 255) part[blockIdx.x] = sm[255];
}

__global__ __launch_bounds__(256) void k_scan2(int* __restrict__ part, int nb){
    __shared__ int sm[256];
    int t = threadIdx.x;
    int c = (t < nb) ? part[t] : 0;
    sm[t] = c;
    __syncthreads();
    for (int off = 1; off < 256; off <<= 1){
        int v = (t >= off) ? sm[t-off] : 0;
        __syncthreads();
        sm[t] += v;
        __syncthreads();
    }
    if (t < nb) part[t] = sm[t] - c;
}

__global__ __launch_bounds__(256) void k_final(int* __restrict__ rs, const int* __restrict__ part,
                                               const int* __restrict__ cnt, float* __restrict__ dinv, int N){
    int i = blockIdx.x*256 + threadIdx.x;
    if (i < N){
        rs[i] += part[i >> 8];
        dinv[i] = rsqrtf((float)cnt[i] + 1.0f);
    }
}

// fill padding slots with index N (zero dummy row); also zero the 4 dummy rows of hwq
__global__ __launch_bounds__(256) void k_pad(const int* __restrict__ cnt, const int* __restrict__ rs,
                                             int* __restrict__ csr, unsigned* __restrict__ hwq, int N){
    int i = blockIdx.x*256 + threadIdx.x;
    if (i < N){
        int c = cnt[i];
        int pc = (c + 15) & ~15;
        int e = rs[i];
        for (int q = c; q < pc; ++q) csr[e+q] = N;
    }
    if (blockIdx.x == 0 && threadIdx.x < 64){
        int p = threadIdx.x >> 4, c = threadIdx.x & 15;
        hwq[((size_t)p*(N+1) + N)*16 + c] = 0u;   // dummy row per pass
    }
}

__global__ __launch_bounds__(256) void k_fill(const int* __restrict__ src, const int* __restrict__ dst,
                                              const int* __restrict__ rs, int* __restrict__ fil,
                                              int* __restrict__ csr, int E){
    int e = blockIdx.x*256 + threadIdx.x;
    if (e < E){
        int d = dst[e];
        int p = atomicAdd(&fil[d], 1);
        csr[rs[d] + p] = src[e];
    }
}

// ---------------- dense matmul: hwq[chunk][r][32] = fp16((A[r,:] @ W) * dinv[r]) ----------------

__global__ __launch_bounds__(256) void k_mm(const float* __restrict__ A, const float* __restrict__ W,
                                            const float* __restrict__ dinv, f16* __restrict__ hwq,
                                            int n, int Np1){
    __shared__ float sW[128*128];
    int t = threadIdx.x;
    for (int idx = t; idx < 4096; idx += 256)
        ((float4*)sW)[idx] = ((const float4*)W)[idx];
    __syncthreads();

    int tx = t & 7, ty = t >> 3;
    int c0 = tx * 16;
    int r0 = blockIdx.x * 128 + ty;

    float acc[4][16];
    #pragma unroll
    for (int i = 0; i < 4; ++i)
        #pragma unroll
        for (int j = 0; j < 16; ++j) acc[i][j] = 0.f;

    for (int k0 = 0; k0 < 128; k0 += 4){
        float4 a[4];
        #pragma unroll
        for (int i = 0; i < 4; ++i){
            int r = r0 + 32*i;
            a[i] = (r < n) ? *(const float4*)&A[(size_t)r*128 + k0] : make_float4(0.f,0.f,0.f,0.f);
        }
        #pragma unroll
        for (int kk = 0; kk < 4; ++kk){
            const float4* wp = (const float4*)&sW[(k0+kk)*128 + c0];
            float4 w0 = wp[0], w1 = wp[1], w2 = wp[2], w3 = wp[3];
            #pragma unroll
            for (int i = 0; i < 4; ++i){
                float av = (kk==0) ? a[i].x : (kk==1) ? a[i].y : (kk==2) ? a[i].z : a[i].w;
                acc[i][ 0] = fmaf(av, w0.x, acc[i][ 0]);
                acc[i][ 1] = fmaf(av, w0.y, acc[i][ 1]);
                acc[i][ 2] = fmaf(av, w0.z, acc[i][ 2]);
                acc[i][ 3] = fmaf(av, w0.w, acc[i][ 3]);
                acc[i][ 4] = fmaf(av, w1.x, acc[i][ 4]);
                acc[i][ 5] = fmaf(av, w1.y, acc[i][ 5]);
                acc[i][ 6] = fmaf(av, w1.z, acc[i][ 6]);
                acc[i][ 7] = fmaf(av, w1.w, acc[i][ 7]);
                acc[i][ 8] = fmaf(av, w2.x, acc[i][ 8]);
                acc[i][ 9] = fmaf(av, w2.y, acc[i][ 9]);
                acc[i][10] = fmaf(av, w2.z, acc[i][10]);
                acc[i][11] = fmaf(av, w2.w, acc[i][11]);
                acc[i][12] = fmaf(av, w3.x, acc[i][12]);
                acc[i][13] = fmaf(av, w3.y, acc[i][13]);
                acc[i][14] = fmaf(av, w3.z, acc[i][14]);
                acc[i][15] = fmaf(av, w3.w, acc[i][15]);
            }
        }
    }

    int chunk = tx >> 1, half = tx & 1;
    #pragma unroll
    for (int i = 0; i < 4; ++i){
        int r = r0 + 32*i;
        if (r < n){
            float di = dinv[r];
            unsigned u[8];
            #pragma unroll
            for (int j = 0; j < 8; ++j){
                f16x2 hp;
                hp.x = (f16)(acc[i][2*j]   * di);
                hp.y = (f16)(acc[i][2*j+1] * di);
                u[j] = __builtin_bit_cast(unsigned, hp);
            }
            uint4* cp = (uint4*)(hwq + ((size_t)chunk*Np1 + r)*32 + half*16);
            cp[0] = make_uint4(u[0],u[1],u[2],u[3]);
            cp[1] = make_uint4(u[4],u[5],u[6],u[7]);
        }
    }
}

// ---------------- aggregation pass p: 32-dim chunk, L2-resident sub-table ----------------
// lane = 16*g + c : group g gathers rows, lane-chunk c owns dims {2c,2c+1} of the 32-dim slice.

__global__ __launch_bounds__(256) void k_agg(const f16* __restrict__ hwq, const float* __restrict__ dinv,
                                             const int* __restrict__ rs, const int* __restrict__ cnt,
                                             const int* __restrict__ csr, const float* __restrict__ bias,
                                             float* __restrict__ hout, int N, int p){
    int wid  = (blockIdx.x*256 + threadIdx.x) >> 6;
    int lane = threadIdx.x & 63;
    if (wid >= N) return;
    wid = __builtin_amdgcn_readfirstlane(wid);
    int g = lane >> 4, c = lane & 15;
    const unsigned* rows = (const unsigned*)(hwq + (size_t)p*(N+1)*32);

    unsigned su = rows[(size_t)((g == 0) ? wid : N)*16 + c];   // self (pre-scaled); others dummy
    float2 sv = h2f(su);
    float2 acc = make_float2(sv.x, sv.y);

    int nb = (cnt[wid] + 15) >> 4;
    const int* cp = csr + rs[wid];
    for (int t = 0; t < nb; ++t){
        intx4 iv = __builtin_nontemporal_load((const intx4*)cp + g);
        cp += 16;
        unsigned u0 = rows[(size_t)iv.x*16 + c];
        unsigned u1 = rows[(size_t)iv.y*16 + c];
        unsigned u2 = rows[(size_t)iv.z*16 + c];
        unsigned u3 = rows[(size_t)iv.w*16 + c];
        float2 v0 = h2f(u0), v1 = h2f(u1), v2 = h2f(u2), v3 = h2f(u3);
        acc.x += (v0.x+v1.x)+(v2.x+v3.x);
        acc.y += (v0.y+v1.y)+(v2.y+v3.y);
    }

    acc.x += __shfl_xor(acc.x, 16); acc.y += __shfl_xor(acc.y, 16);
    acc.x += __shfl_xor(acc.x, 32); acc.y += __shfl_xor(acc.y, 32);

    if (lane < 16){
        float di = dinv[wid];
        float2 b2 = ((const float2*)bias)[p*16 + c];
        fltx2 o;
        o.x = fmaxf(fmaf(acc.x, di, b2.x), 0.f);
        o.y = fmaxf(fmaf(acc.y, di, b2.y), 0.f);
        __builtin_nontemporal_store(o, (fltx2*)&hout[(size_t)wid*128 + p*32 + 2*c]);
    }
}

// layer 3 pass p: no relu; partial dot with Wo chunk; atomicAdd into out[graph]
__global__ __launch_bounds__(256) void k_agg_pool(const f16* __restrict__ hwq, const float* __restrict__ dinv,
                                                  const int* __restrict__ rs, const int* __restrict__ cnt,
                                                  const int* __restrict__ csr, const float* __restrict__ bias,
                                                  const float* __restrict__ Wo, const int* __restrict__ batch,
                                                  float* __restrict__ out, int N, int p){
    int wid  = (blockIdx.x*256 + threadIdx.x) >> 6;
    int lane = threadIdx.x & 63;
    if (wid >= N) return;
    wid = __builtin_amdgcn_readfirstlane(wid);
    int g = lane >> 4, c = lane & 15;
    const unsigned* rows = (const unsigned*)(hwq + (size_t)p*(N+1)*32);

    unsigned su = rows[(size_t)((g == 0) ? wid : N)*16 + c];
    float2 sv = h2f(su);
    float2 acc = make_float2(sv.x, sv.y);

    int nb = (cnt[wid] + 15) >> 4;
    const int* cp = csr + rs[wid];
    for (int t = 0; t < nb; ++t){
        intx4 iv = __builtin_nontemporal_load((const intx4*)cp + g);
        cp += 16;
        unsigned u0 = rows[(size_t)iv.x*16 + c];
        unsigned u1 = rows[(size_t)iv.y*16 + c];
        unsigned u2 = rows[(size_t)iv.z*16 + c];
        unsigned u3 = rows[(size_t)iv.w*16 + c];
        float2 v0 = h2f(u0), v1 = h2f(u1), v2 = h2f(u2), v3 = h2f(u3);
        acc.x += (v0.x+v1.x)+(v2.x+v3.x);
        acc.y += (v0.y+v1.y)+(v2.y+v3.y);
    }

    acc.x += __shfl_xor(acc.x, 16); acc.y += __shfl_xor(acc.y, 16);
    acc.x += __shfl_xor(acc.x, 32); acc.y += __shfl_xor(acc.y, 32);

    float di = dinv[wid];
    float2 b2 = ((const float2*)bias)[p*16 + c];
    float2 w2 = ((const float2*)Wo)[p*16 + c];
    float sdot = fmaf(acc.x, di, b2.x)*w2.x + fmaf(acc.y, di, b2.y)*w2.y;
    sdot += __shfl_xor(sdot, 1);
    sdot += __shfl_xor(sdot, 2);
    sdot += __shfl_xor(sdot, 4);
    sdot += __shfl_xor(sdot, 8);
    if (lane == 0) atomicAdd(&out[batch[wid]], sdot);
}

__global__ __launch_bounds__(256) void k_init_out(float* __restrict__ out, const float* __restrict__ bo, int G){
    int g = blockIdx.x*256 + threadIdx.x;
    if (g < G) out[g] = bo[0];
}

// ---------------- launch ----------------

extern "C" void kernel_launch(void* const* d_in, const int* in_sizes, int n_in,
                              void* d_out, int out_size, void* d_ws, size_t ws_size,
                              hipStream_t stream) {
    const float* x     = (const float*)d_in[0];
    const int*   ei    = (const int*)d_in[1];
    const int*   batch = (const int*)d_in[2];
    const float* W1 = (const float*)d_in[3];
    const float* b1 = (const float*)d_in[4];
    const float* W2 = (const float*)d_in[5];
    const float* b2 = (const float*)d_in[6];
    const float* W3 = (const float*)d_in[7];
    const float* b3 = (const float*)d_in[8];
    const float* Wo = (const float*)d_in[9];
    const float* bo = (const float*)d_in[10];

    int N = in_sizes[0] / 128;
    int E = in_sizes[1] / 2;
    int G = out_size;
    const int* srcI = ei;
    const int* dstI = ei + E;

    char* p = (char*)d_ws;
    size_t off = 0;
    auto alloc = [&](size_t bytes) -> void* {
        void* r = p + off;
        off += (bytes + 255) & ~(size_t)255;
        return r;
    };
    f16*   hwq  = (f16*)alloc((size_t)4*(N+1)*32*sizeof(f16));     // pass-major, dummy row per pass
    float* h    = (float*)alloc((size_t)N*128*sizeof(float));
    float* dinv = (float*)alloc((size_t)N*sizeof(float));
    int*   cnt  = (int*)alloc((size_t)N*sizeof(int));
    int*   fil  = (int*)alloc((size_t)N*sizeof(int));
    int*   rs   = (int*)alloc((size_t)(N+1)*sizeof(int));
    int*   part = (int*)alloc(1024);
    int*   csr  = (int*)alloc(((size_t)E + 16*(size_t)N)*sizeof(int));

    hipMemsetAsync(cnt, 0, (size_t)N*sizeof(int), stream);
    hipMemsetAsync(fil, 0, (size_t)N*sizeof(int), stream);

    int nbE = (E + 255)/256;
    int nbN = (N + 255)/256;
    k_count<<<nbE, 256, 0, stream>>>(dstI, cnt, E);
    k_scan1<<<nbN, 256, 0, stream>>>(cnt, rs, part, N);
    k_scan2<<<1,   256, 0, stream>>>(part, nbN);
    k_final<<<nbN, 256, 0, stream>>>(rs, part, cnt, dinv, N);
    k_pad  <<<nbN, 256, 0, stream>>>(cnt, rs, csr, (unsigned*)hwq, N);
    k_fill <<<nbE, 256, 0, stream>>>(srcI, dstI, rs, fil, csr, E);

    int nbM = (N + 127)/128;
    int nbA = (N + 3)/4;   // 4 nodes (waves) per 256-thread block

    k_mm <<<nbM, 256, 0, stream>>>(x, W1, dinv, hwq, N, N+1);
    for (int q = 0; q < 4; ++q)
        k_agg<<<nbA, 256, 0, stream>>>(hwq, dinv, rs, cnt, csr, b1, h, N, q);
    k_mm <<<nbM, 256, 0, stream>>>(h, W2, dinv, hwq, N, N+1);
    for (int q = 0; q < 4; ++q)
        k_agg<<<nbA, 256, 0, stream>>>(hwq, dinv, rs, cnt, csr, b2, h, N, q);
    k_mm <<<nbM, 256, 0, stream>>>(h, W3, dinv, hwq, N, N+1);
    k_init_out<<<(G + 255)/256, 256, 0, stream>>>((float*)d_out, bo, G);
    for (int q = 0; q < 4; ++q)
        k_agg_pool<<<nbA, 256, 0, stream>>>(hwq, dinv, rs, cnt, csr, b3, Wo, batch, (float*)d_out, N, q);
}

// Round 7
// 293.117 us; speedup vs baseline: 2.7033x; 2.7033x over previous
//
#include <hip/hip_runtime.h>

typedef _Float16 f16;
typedef __attribute__((ext_vector_type(2))) _Float16 f16x2;
typedef __attribute__((ext_vector_type(8))) _Float16 f16x8;
typedef __attribute__((ext_vector_type(4))) float f32x4;
typedef __attribute__((ext_vector_type(4))) int intx4;

__device__ inline float2 h2f(unsigned u){
    f16x2 h = __builtin_bit_cast(f16x2, u);
    return make_float2((float)h.x, (float)h.y);
}

__device__ inline void addrow(float* acc, uint4 u){
    float2 p0 = h2f(u.x), p1 = h2f(u.y), p2 = h2f(u.z), p3 = h2f(u.w);
    acc[0] += p0.x; acc[1] += p0.y; acc[2] += p1.x; acc[3] += p1.y;
    acc[4] += p2.x; acc[5] += p2.y; acc[6] += p3.x; acc[7] += p3.y;
}

// ---------------- CSR build (padded to multiples of 16 per node) ----------------

__global__ __launch_bounds__(256) void k_count(const int* __restrict__ dst, int* __restrict__ cnt, int E){
    int e = blockIdx.x*256 + threadIdx.x;
    if (e < E) atomicAdd(&cnt[dst[e]], 1);
}

__global__ __launch_bounds__(256) void k_scan1(const int* __restrict__ cnt, int* __restrict__ rs,
                                               int* __restrict__ part, int N){
    __shared__ int sm[256];
    int t = threadIdx.x;
    int i = blockIdx.x*256 + t;
    int c = (i < N) ? ((cnt[i] + 15) & ~15) : 0;
    sm[t] = c;
    __syncthreads();
    for (int off = 1; off < 256; off <<= 1){
        int v = (t >= off) ? sm[t-off] : 0;
        __syncthreads();
        sm[t] += v;
        __syncthreads();
    }
    if (i < N) rs[i] = sm[t] - c;
    if (t == 255) part[blockIdx.x] = sm[255];
}

__global__ __launch_bounds__(256) void k_scan2(int* __restrict__ part, int nb){
    __shared__ int sm[256];
    int t = threadIdx.x;
    int c = (t < nb) ? part[t] : 0;
    sm[t] = c;
    __syncthreads();
    for (int off = 1; off < 256; off <<= 1){
        int v = (t >= off) ? sm[t-off] : 0;
        __syncthreads();
        sm[t] += v;
        __syncthreads();
    }
    if (t < nb) part[t] = sm[t] - c;
}

// finalize rs, compute dinv, pad csr tail slots with N, zero dummy hw row
__global__ __launch_bounds__(256) void k_final(int* __restrict__ rs, const int* __restrict__ part,
                                               const int* __restrict__ cnt, float* __restrict__ dinv,
                                               int* __restrict__ csr, uint4* __restrict__ hwrows, int N){
    int i = blockIdx.x*256 + threadIdx.x;
    if (i < N){
        int r = rs[i] + part[i >> 8];
        rs[i] = r;
        int c = cnt[i];
        dinv[i] = rsqrtf((float)c + 1.0f);
        int pc = (c + 15) & ~15;
        for (int q = c; q < pc; ++q) csr[r+q] = N;
    }
    if (blockIdx.x == 0 && threadIdx.x < 16)
        hwrows[(size_t)N*16 + threadIdx.x] = make_uint4(0,0,0,0);   // zero dummy row
}

__global__ __launch_bounds__(256) void k_fill(const int* __restrict__ src, const int* __restrict__ dst,
                                              const int* __restrict__ rs, int* __restrict__ fil,
                                              int* __restrict__ csr, int E){
    int e = blockIdx.x*256 + threadIdx.x;
    if (e < E){
        int d = dst[e];
        int p = atomicAdd(&fil[d], 1);
        csr[rs[d] + p] = src[e];
    }
}

// ---------------- MFMA matmul: C[r,:] = fp16((A[r,:] @ W) * dinv[r]) ----------------
// block = 256 (4 waves), 64 rows/block; W^T fp16 staged in LDS.
// A/B fragments both use k-index map sigma(g,j)=g*8+j (permutation-safe);
// C/D layout: col = lane&15, row = (lane>>4)*4 + reg  [verified m89].

#define LDW 136

template<int AFP16>
__global__ __launch_bounds__(256) void k_mm(const void* __restrict__ Av, const float* __restrict__ W,
                                            const float* __restrict__ dinv, f16* __restrict__ C, int n){
    __shared__ __align__(16) _Float16 sWt[128*LDW];
    __shared__ __align__(16) _Float16 sOut[4][16*LDW];
    int t = threadIdx.x;
    for (int idx = t; idx < 4096; idx += 256){
        int k = idx >> 5, c4 = (idx & 31) * 4;
        float4 w = ((const float4*)W)[idx];      // W[k][c4..c4+3]
        sWt[(c4+0)*LDW + k] = (f16)w.x;
        sWt[(c4+1)*LDW + k] = (f16)w.y;
        sWt[(c4+2)*LDW + k] = (f16)w.z;
        sWt[(c4+3)*LDW + k] = (f16)w.w;
    }
    __syncthreads();

    int wv = t >> 6, l = t & 63;
    int r16 = l & 15, g = l >> 4;
    int r0 = blockIdx.x * 64 + wv * 16;

    int arow = r0 + r16;
    bool aok = arow < n;
    f16x8 a[4];
    #pragma unroll
    for (int s = 0; s < 4; ++s){
        if (AFP16){
            const f16* A = (const f16*)Av;
            a[s] = aok ? *(const f16x8*)&A[(size_t)arow*128 + s*32 + g*8] : (f16x8)(_Float16)0.f;
        } else {
            const float* A = (const float*)Av;
            f16x8 av = (f16x8)(_Float16)0.f;
            if (aok){
                const float4* ap = (const float4*)&A[(size_t)arow*128 + s*32 + g*8];
                float4 x0 = ap[0], x1 = ap[1];
                av[0]=(f16)x0.x; av[1]=(f16)x0.y; av[2]=(f16)x0.z; av[3]=(f16)x0.w;
                av[4]=(f16)x1.x; av[5]=(f16)x1.y; av[6]=(f16)x1.z; av[7]=(f16)x1.w;
            }
            a[s] = av;
        }
    }

    f32x4 acc[8];
    #pragma unroll
    for (int ct = 0; ct < 8; ++ct) acc[ct] = (f32x4)0.f;

    #pragma unroll
    for (int ct = 0; ct < 8; ++ct){
        int c = ct*16 + r16;
        #pragma unroll
        for (int s = 0; s < 4; ++s){
            f16x8 b = *(const f16x8*)&sWt[c*LDW + s*32 + g*8];
            acc[ct] = __builtin_amdgcn_mfma_f32_16x16x32_f16(a[s], b, acc[ct], 0, 0, 0);
        }
    }

    float dv[4];
    #pragma unroll
    for (int j = 0; j < 4; ++j){
        int rr = r0 + g*4 + j;
        dv[j] = (rr < n) ? dinv[rr] : 0.f;
    }
    #pragma unroll
    for (int ct = 0; ct < 8; ++ct)
        #pragma unroll
        for (int j = 0; j < 4; ++j)
            sOut[wv][(g*4+j)*LDW + ct*16 + r16] = (f16)(acc[ct][j] * dv[j]);
    __syncthreads();

    int orow = r0 + r16;
    if (orow < n){
        const f16x8* srcp = (const f16x8*)&sOut[wv][r16*LDW + g*32];
        f16x8 o0 = srcp[0], o1 = srcp[1], o2 = srcp[2], o3 = srcp[3];
        f16x8* dstp = (f16x8*)&C[(size_t)orow*128 + g*32];
        dstp[0]=o0; dstp[1]=o1; dstp[2]=o2; dstp[3]=o3;
    }
}

// ---------------- aggregation: 2 nodes per wave, 16B/lane gathers ----------------
// lane = 16*g + c : group g gathers rows, chunk c owns dims 8c..8c+7.

__global__ __launch_bounds__(256) void k_agg2(const f16* __restrict__ hw, const float* __restrict__ dinv,
                                              const int* __restrict__ rs, const int* __restrict__ cnt,
                                              const int* __restrict__ csr, const float* __restrict__ bias,
                                              f16* __restrict__ hout, int N){
    int wvi = (blockIdx.x*256 + threadIdx.x) >> 6;
    int l = threadIdx.x & 63;
    int w0 = wvi*2;
    if (w0 >= N) return;
    w0 = __builtin_amdgcn_readfirstlane(w0);
    int w1 = w0 + 1;                     // N even
    int g = l >> 4, c = l & 15;
    const uint4* rows = (const uint4*)hw;

    float acc0[8] = {0,0,0,0,0,0,0,0};
    float acc1[8] = {0,0,0,0,0,0,0,0};
    uint4 s0 = rows[(size_t)((g==0) ? w0 : N)*16 + c]; addrow(acc0, s0);
    uint4 s1 = rows[(size_t)((g==1) ? w1 : N)*16 + c]; addrow(acc1, s1);

    int nb0 = (cnt[w0] + 15) >> 4, nb1 = (cnt[w1] + 15) >> 4;
    const int* cp0 = csr + rs[w0];
    const int* cp1 = csr + rs[w1];
    int nbm = nb0 > nb1 ? nb0 : nb1;
    for (int t2 = 0; t2 < nbm; ++t2){
        if (t2 < nb0){
            intx4 iv = __builtin_nontemporal_load((const intx4*)cp0 + g); cp0 += 16;
            uint4 r0 = rows[(size_t)iv.x*16 + c];
            uint4 r1 = rows[(size_t)iv.y*16 + c];
            uint4 r2 = rows[(size_t)iv.z*16 + c];
            uint4 r3 = rows[(size_t)iv.w*16 + c];
            addrow(acc0, r0); addrow(acc0, r1); addrow(acc0, r2); addrow(acc0, r3);
        }
        if (t2 < nb1){
            intx4 iv = __builtin_nontemporal_load((const intx4*)cp1 + g); cp1 += 16;
            uint4 r0 = rows[(size_t)iv.x*16 + c];
            uint4 r1 = rows[(size_t)iv.y*16 + c];
            uint4 r2 = rows[(size_t)iv.z*16 + c];
            uint4 r3 = rows[(size_t)iv.w*16 + c];
            addrow(acc1, r0); addrow(acc1, r1); addrow(acc1, r2); addrow(acc1, r3);
        }
    }

    #pragma unroll
    for (int j = 0; j < 8; ++j){
        acc0[j] += __shfl_xor(acc0[j], 16); acc0[j] += __shfl_xor(acc0[j], 32);
        acc1[j] += __shfl_xor(acc1[j], 16); acc1[j] += __shfl_xor(acc1[j], 32);
    }

    if (l < 32){
        int node = (l < 16) ? w0 : w1;
        float di = dinv[node];
        float v[8];
        #pragma unroll
        for (int j = 0; j < 8; ++j) v[j] = (l < 16) ? acc0[j] : acc1[j];
        int cc = l & 15;
        const float4* bp = (const float4*)bias + cc*2;
        float4 b0 = bp[0], b1 = bp[1];
        f16x8 o;
        o[0]=(f16)fmaxf(fmaf(v[0],di,b0.x),0.f); o[1]=(f16)fmaxf(fmaf(v[1],di,b0.y),0.f);
        o[2]=(f16)fmaxf(fmaf(v[2],di,b0.z),0.f); o[3]=(f16)fmaxf(fmaf(v[3],di,b0.w),0.f);
        o[4]=(f16)fmaxf(fmaf(v[4],di,b1.x),0.f); o[5]=(f16)fmaxf(fmaf(v[5],di,b1.y),0.f);
        o[6]=(f16)fmaxf(fmaf(v[6],di,b1.z),0.f); o[7]=(f16)fmaxf(fmaf(v[7],di,b1.w),0.f);
        *(f16x8*)&hout[(size_t)node*128 + cc*8] = o;
    }
}

// layer 3: no relu; fused pool + output head
__global__ __launch_bounds__(256) void k_pool2(const f16* __restrict__ hw, const float* __restrict__ dinv,
                                               const int* __restrict__ rs, const int* __restrict__ cnt,
                                               const int* __restrict__ csr, const float* __restrict__ bias,
                                               const float* __restrict__ Wo, const int* __restrict__ batch,
                                               float* __restrict__ out, int N){
    int wvi = (blockIdx.x*256 + threadIdx.x) >> 6;
    int l = threadIdx.x & 63;
    int w0 = wvi*2;
    if (w0 >= N) return;
    w0 = __builtin_amdgcn_readfirstlane(w0);
    int w1 = w0 + 1;
    int g = l >> 4, c = l & 15;
    const uint4* rows = (const uint4*)hw;

    float acc0[8] = {0,0,0,0,0,0,0,0};
    float acc1[8] = {0,0,0,0,0,0,0,0};
    uint4 s0 = rows[(size_t)((g==0) ? w0 : N)*16 + c]; addrow(acc0, s0);
    uint4 s1 = rows[(size_t)((g==1) ? w1 : N)*16 + c]; addrow(acc1, s1);

    int nb0 = (cnt[w0] + 15) >> 4, nb1 = (cnt[w1] + 15) >> 4;
    const int* cp0 = csr + rs[w0];
    const int* cp1 = csr + rs[w1];
    int nbm = nb0 > nb1 ? nb0 : nb1;
    for (int t2 = 0; t2 < nbm; ++t2){
        if (t2 < nb0){
            intx4 iv = __builtin_nontemporal_load((const intx4*)cp0 + g); cp0 += 16;
            uint4 r0 = rows[(size_t)iv.x*16 + c];
            uint4 r1 = rows[(size_t)iv.y*16 + c];
            uint4 r2 = rows[(size_t)iv.z*16 + c];
            uint4 r3 = rows[(size_t)iv.w*16 + c];
            addrow(acc0, r0); addrow(acc0, r1); addrow(acc0, r2); addrow(acc0, r3);
        }
        if (t2 < nb1){
            intx4 iv = __builtin_nontemporal_load((const intx4*)cp1 + g); cp1 += 16;
            uint4 r0 = rows[(size_t)iv.x*16 + c];
            uint4 r1 = rows[(size_t)iv.y*16 + c];
            uint4 r2 = rows[(size_t)iv.z*16 + c];
            uint4 r3 = rows[(size_t)iv.w*16 + c];
            addrow(acc1, r0); addrow(acc1, r1); addrow(acc1, r2); addrow(acc1, r3);
        }
    }

    #pragma unroll
    for (int j = 0; j < 8; ++j){
        acc0[j] += __shfl_xor(acc0[j], 16); acc0[j] += __shfl_xor(acc0[j], 32);
        acc1[j] += __shfl_xor(acc1[j], 16); acc1[j] += __shfl_xor(acc1[j], 32);
    }

    // lanes 0-15: node0 partial dot; lanes 16-31: node1
    int node = (l < 16) ? w0 : w1;
    float di = dinv[node];
    float v[8];
    #pragma unroll
    for (int j = 0; j < 8; ++j) v[j] = (l < 16) ? acc0[j] : acc1[j];
    int cc = l & 15;
    const float4* bp = (const float4*)bias + cc*2;
    const float4* wp = (const float4*)Wo   + cc*2;
    float4 b0 = bp[0], b1 = bp[1];
    float4 q0 = wp[0], q1 = wp[1];
    float sd = fmaf(v[0],di,b0.x)*q0.x + fmaf(v[1],di,b0.y)*q0.y
             + fmaf(v[2],di,b0.z)*q0.z + fmaf(v[3],di,b0.w)*q0.w
             + fmaf(v[4],di,b1.x)*q1.x + fmaf(v[5],di,b1.y)*q1.y
             + fmaf(v[6],di,b1.z)*q1.z + fmaf(v[7],di,b1.w)*q1.w;
    sd += __shfl_xor(sd, 1);
    sd += __shfl_xor(sd, 2);
    sd += __shfl_xor(sd, 4);
    sd += __shfl_xor(sd, 8);
    float sd1 = __shfl(sd, 16);          // UNIFORM: all lanes execute (R6 bug was divergent shfl)
    if (l == 0){
        int b0i = batch[w0], b1i = batch[w1];
        if (b0i == b1i) atomicAdd(&out[b0i], sd + sd1);
        else { atomicAdd(&out[b0i], sd); atomicAdd(&out[b1i], sd1); }
    }
}

__global__ __launch_bounds__(256) void k_init_out(float* __restrict__ out, const float* __restrict__ bo, int G){
    int g = blockIdx.x*256 + threadIdx.x;
    if (g < G) out[g] = bo[0];
}

// ---------------- launch ----------------

extern "C" void kernel_launch(void* const* d_in, const int* in_sizes, int n_in,
                              void* d_out, int out_size, void* d_ws, size_t ws_size,
                              hipStream_t stream) {
    const float* x     = (const float*)d_in[0];
    const int*   ei    = (const int*)d_in[1];
    const int*   batch = (const int*)d_in[2];
    const float* W1 = (const float*)d_in[3];
    const float* b1 = (const float*)d_in[4];
    const float* W2 = (const float*)d_in[5];
    const float* b2 = (const float*)d_in[6];
    const float* W3 = (const float*)d_in[7];
    const float* b3 = (const float*)d_in[8];
    const float* Wo = (const float*)d_in[9];
    const float* bo = (const float*)d_in[10];

    int N = in_sizes[0] / 128;
    int E = in_sizes[1] / 2;
    int G = out_size;
    const int* srcI = ei;
    const int* dstI = ei + E;

    char* p = (char*)d_ws;
    size_t off = 0;
    auto alloc = [&](size_t bytes) -> void* {
        void* r = p + off;
        off += (bytes + 255) & ~(size_t)255;
        return r;
    };
    f16*   hw   = (f16*)alloc((size_t)(N+1)*128*sizeof(f16));   // row N = zero dummy
    f16*   h    = (f16*)alloc((size_t)N*128*sizeof(f16));
    float* dinv = (float*)alloc((size_t)N*sizeof(float));
    int*   cnt  = (int*)alloc((size_t)N*sizeof(int));
    int*   fil  = (int*)alloc((size_t)N*sizeof(int));
    int*   rs   = (int*)alloc((size_t)(N+1)*sizeof(int));
    int*   part = (int*)alloc(1024);
    int*   csr  = (int*)alloc(((size_t)E + 16*(size_t)N)*sizeof(int));

    hipMemsetAsync(cnt, 0, (size_t)N*sizeof(int), stream);
    hipMemsetAsync(fil, 0, (size_t)N*sizeof(int), stream);

    int nbE = (E + 255)/256;
    int nbN = (N + 255)/256;   // 196 <= 256, required by k_scan2
    k_count<<<nbE, 256, 0, stream>>>(dstI, cnt, E);
    k_scan1<<<nbN, 256, 0, stream>>>(cnt, rs, part, N);
    k_scan2<<<1,   256, 0, stream>>>(part, nbN);
    k_final<<<nbN, 256, 0, stream>>>(rs, part, cnt, dinv, csr, (uint4*)hw, N);
    k_fill <<<nbE, 256, 0, stream>>>(srcI, dstI, rs, fil, csr, E);

    int nbM = (N + 63)/64;
    int nbA = (int)(((size_t)((N+1)/2)*64 + 255)/256);

    k_mm<0><<<nbM, 256, 0, stream>>>(x, W1, dinv, hw, N);
    k_agg2 <<<nbA, 256, 0, stream>>>(hw, dinv, rs, cnt, csr, b1, h, N);
    k_mm<1><<<nbM, 256, 0, stream>>>(h, W2, dinv, hw, N);
    k_agg2 <<<nbA, 256, 0, stream>>>(hw, dinv, rs, cnt, csr, b2, h, N);
    k_mm<1><<<nbM, 256, 0, stream>>>(h, W3, dinv, hw, N);
    k_init_out<<<(G + 255)/256, 256, 0, stream>>>((float*)d_out, bo, G);
    k_pool2<<<nbA, 256, 0, stream>>>(hw, dinv, rs, cnt, csr, b3, Wo, batch, (float*)d_out, N);
}